// Round 1
// baseline (508.914 us; speedup 1.0000x reference)
//
#include <hip/hip_runtime.h>
#include <hip/hip_bf16.h>

#define SEQ 192
#define DIMK 384
#define NHEAD 8
#define DHEAD 48
#define NB 2

typedef __attribute__((ext_vector_type(8))) short short8;
typedef __attribute__((ext_vector_type(4))) float f32x4;
typedef __attribute__((ext_vector_type(4))) unsigned int u32x4;

__device__ __forceinline__ unsigned short f2bf(float f) {
    unsigned int u = __builtin_bit_cast(unsigned int, f);
    u += 0x7FFFu + ((u >> 16) & 1u);
    return (unsigned short)(u >> 16);
}

// ---------------- Kernel 1: LayerNorm -> bf16 xn ----------------
__global__ __launch_bounds__(64) void ln_kernel(const float* __restrict__ x,
                                                const float* __restrict__ gamma,
                                                const float* __restrict__ beta,
                                                unsigned short* __restrict__ xn) {
    int row = blockIdx.x;
    int l = threadIdx.x;
    const float* xr = x + (size_t)row * DIMK;
    float v[6];
    float s = 0.f, s2 = 0.f;
#pragma unroll
    for (int k = 0; k < 6; ++k) {
        v[k] = xr[l + 64 * k];
        s += v[k];
        s2 += v[k] * v[k];
    }
#pragma unroll
    for (int off = 32; off > 0; off >>= 1) {
        s += __shfl_xor(s, off, 64);
        s2 += __shfl_xor(s2, off, 64);
    }
    float mu = s * (1.f / 384.f);
    float var = s2 * (1.f / 384.f) - mu * mu;
    float inv = rsqrtf(var + 1e-5f);
#pragma unroll
    for (int k = 0; k < 6; ++k) {
        int c = l + 64 * k;
        float o = (v[k] - mu) * inv * gamma[c] + beta[c];
        xn[(size_t)row * DIMK + c] = f2bf(o);
    }
}

// ---------------- shared helper: 384-row GEMM on one 48-col slice ----------
// A: [384][384] bf16 (ushort), W: [384][384] fp32 row-major, out fp32 [384][384]
// block = 256 threads (4 waves), each wave covers 96 rows.
__device__ __forceinline__ void gemm384_48(const unsigned short* __restrict__ A,
                                           const float* __restrict__ W,
                                           float* __restrict__ outp,
                                           const float* __restrict__ bias,
                                           int nbase, char* lds_raw) {
    const int tid = threadIdx.x;
    const int wave = tid >> 6, lane = tid & 63;
    const int quad = lane >> 4, l15 = lane & 15;
    f32x4 acc[6][3];
#pragma unroll
    for (int p = 0; p < 6; ++p)
#pragma unroll
        for (int nt = 0; nt < 3; ++nt) acc[p][nt] = f32x4{0.f, 0.f, 0.f, 0.f};
    u32x4* stage = (u32x4*)lds_raw;
    for (int chunk = 0; chunk < 6; ++chunk) {
#pragma unroll
        for (int blk = wave; blk < 6; blk += 4) {
            int kk = blk / 3, nt = blk % 3;
            int k0 = chunk * 64 + kk * 32 + quad * 8;
            int n = nbase + nt * 16 + l15;
            const float* src = W + (size_t)k0 * DIMK + n;
            float f[8];
#pragma unroll
            for (int j = 0; j < 8; ++j) f[j] = src[(size_t)j * DIMK];
            u32x4 pk;
            pk.x = (unsigned)f2bf(f[0]) | ((unsigned)f2bf(f[1]) << 16);
            pk.y = (unsigned)f2bf(f[2]) | ((unsigned)f2bf(f[3]) << 16);
            pk.z = (unsigned)f2bf(f[4]) | ((unsigned)f2bf(f[5]) << 16);
            pk.w = (unsigned)f2bf(f[6]) | ((unsigned)f2bf(f[7]) << 16);
            stage[blk * 64 + lane] = pk;
        }
        __syncthreads();
#pragma unroll
        for (int kk = 0; kk < 2; ++kk) {
            short8 bfrag[3];
#pragma unroll
            for (int nt = 0; nt < 3; ++nt)
                bfrag[nt] = __builtin_bit_cast(short8, stage[(kk * 3 + nt) * 64 + lane]);
#pragma unroll
            for (int p = 0; p < 6; ++p) {
                int r = wave * 96 + p * 16 + l15;
                const u32x4* ap =
                    (const u32x4*)(A + (size_t)r * DIMK + chunk * 64 + kk * 32 + quad * 8);
                short8 af = __builtin_bit_cast(short8, *ap);
#pragma unroll
                for (int nt = 0; nt < 3; ++nt)
                    acc[p][nt] =
                        __builtin_amdgcn_mfma_f32_16x16x32_bf16(af, bfrag[nt], acc[p][nt], 0, 0, 0);
            }
        }
        __syncthreads();
    }
#pragma unroll
    for (int p = 0; p < 6; ++p)
#pragma unroll
        for (int nt = 0; nt < 3; ++nt) {
            int col = nbase + nt * 16 + l15;
            float badd = bias ? bias[col] : 0.f;
#pragma unroll
            for (int r = 0; r < 4; ++r) {
                int row = wave * 96 + p * 16 + quad * 4 + r;
                outp[(size_t)row * DIMK + col] = acc[p][nt][r] + badd;
            }
        }
}

// ---------------- Kernel 3: per-offset QK dots (+ folded v-projection) ----------
// grid: 1536 qk jobs (bx = h*192 + o) + 8 v jobs. block=256.
__global__ __launch_bounds__(256) void qk_dots_kernel(const unsigned short* __restrict__ xn,
                                                      const float* __restrict__ uq,
                                                      const float* __restrict__ uk,
                                                      const float* __restrict__ wv,
                                                      float* __restrict__ dots,
                                                      float* __restrict__ vout) {
    __shared__ __align__(16) char lds_raw[18432];
    const int bx = blockIdx.x;
    if (bx >= 1536) {
        gemm384_48(xn, wv, vout, nullptr, (bx - 1536) * DHEAD, lds_raw);
        return;
    }
    const int tid = threadIdx.x;
    const int wave = tid >> 6, lane = tid & 63;
    const int quad = lane >> 4, l15 = lane & 15;
    const int o = bx % 192;
    const int h = bx / 192;
    const int Lo = SEQ - o;
    const int Mrows = 2 * Lo;
    const float* Wq = uq + (size_t)(191 - o) * (DIMK * DIMK);
    const float* Wk = uk + (size_t)o * (DIMK * DIMK);
    const int side = wave >> 1;  // 0 = q (waves 0,1), 1 = k (waves 2,3)
    const int wrow = wave & 1;   // row-half within side
    const int npass = (o < 96) ? 2 : 1;
    u32x4* stage = (u32x4*)lds_raw;
    float* epi = (float*)lds_raw;

    for (int pass = 0; pass < npass; ++pass) {
        const int rowbase = pass * 192 + wrow * 96;
        const bool active = rowbase < Mrows;  // wave-uniform
        f32x4 acc[6][3];
#pragma unroll
        for (int p = 0; p < 6; ++p)
#pragma unroll
            for (int nt = 0; nt < 3; ++nt) acc[p][nt] = f32x4{0.f, 0.f, 0.f, 0.f};

        for (int chunk = 0; chunk < 6; ++chunk) {
            // ---- stage both W slices (bf16, B-fragment layout) ----
#pragma unroll
            for (int blk = wave; blk < 12; blk += 4) {
                int s = blk / 6;
                int rem = blk % 6;
                int kk = rem / 3, nt = rem % 3;
                const float* W = s ? Wk : Wq;
                int k0 = chunk * 64 + kk * 32 + quad * 8;
                int n = h * DHEAD + nt * 16 + l15;
                const float* src = W + (size_t)k0 * DIMK + n;
                float f[8];
#pragma unroll
                for (int j = 0; j < 8; ++j) f[j] = src[(size_t)j * DIMK];
                u32x4 pk;
                pk.x = (unsigned)f2bf(f[0]) | ((unsigned)f2bf(f[1]) << 16);
                pk.y = (unsigned)f2bf(f[2]) | ((unsigned)f2bf(f[3]) << 16);
                pk.z = (unsigned)f2bf(f[4]) | ((unsigned)f2bf(f[5]) << 16);
                pk.w = (unsigned)f2bf(f[6]) | ((unsigned)f2bf(f[7]) << 16);
                stage[blk * 64 + lane] = pk;
            }
            __syncthreads();
            if (active) {
#pragma unroll
                for (int kk = 0; kk < 2; ++kk) {
                    short8 bfrag[3];
#pragma unroll
                    for (int nt = 0; nt < 3; ++nt)
                        bfrag[nt] =
                            __builtin_bit_cast(short8, stage[(side * 6 + kk * 3 + nt) * 64 + lane]);
#pragma unroll
                    for (int p = 0; p < 6; ++p) {
                        int r = rowbase + p * 16 + l15;
                        int bb = (r >= Lo) ? 1 : 0;
                        int t = r - bb * Lo;
                        int g = bb * SEQ + t + (side == 0 ? o : 0);
                        if (r >= Mrows) g = 0;
                        const u32x4* ap = (const u32x4*)(xn + (size_t)g * DIMK + chunk * 64 +
                                                         kk * 32 + quad * 8);
                        short8 af = __builtin_bit_cast(short8, *ap);
#pragma unroll
                        for (int nt = 0; nt < 3; ++nt)
                            acc[p][nt] = __builtin_amdgcn_mfma_f32_16x16x32_bf16(
                                af, bfrag[nt], acc[p][nt], 0, 0, 0);
                    }
                }
            }
            __syncthreads();
        }

        // ---- epilogue: pair Q (waves 0,1) with K (waves 2,3) via LDS ----
#pragma unroll
        for (int ph = 0; ph < 2; ++ph) {
            if (side == 1 && wrow == ph && active) {
#pragma unroll
                for (int p = 0; p < 6; ++p)
#pragma unroll
                    for (int nt = 0; nt < 3; ++nt)
#pragma unroll
                        for (int r = 0; r < 4; ++r)
                            epi[((p * 3 + nt) * 4 + r) * 64 + lane] = acc[p][nt][r];
            }
            __syncthreads();
            if (side == 0 && wrow == ph && active) {
#pragma unroll
                for (int p = 0; p < 6; ++p) {
                    float d0 = 0.f, d1 = 0.f, d2 = 0.f, d3 = 0.f;
#pragma unroll
                    for (int nt = 0; nt < 3; ++nt) {
                        d0 += acc[p][nt][0] * epi[((p * 3 + nt) * 4 + 0) * 64 + lane];
                        d1 += acc[p][nt][1] * epi[((p * 3 + nt) * 4 + 1) * 64 + lane];
                        d2 += acc[p][nt][2] * epi[((p * 3 + nt) * 4 + 2) * 64 + lane];
                        d3 += acc[p][nt][3] * epi[((p * 3 + nt) * 4 + 3) * 64 + lane];
                    }
#pragma unroll
                    for (int mm = 1; mm <= 8; mm <<= 1) {
                        d0 += __shfl_xor(d0, mm, 64);
                        d1 += __shfl_xor(d1, mm, 64);
                        d2 += __shfl_xor(d2, mm, 64);
                        d3 += __shfl_xor(d3, mm, 64);
                    }
                    if (l15 == 0) {
                        float dv[4] = {d0, d1, d2, d3};
#pragma unroll
                        for (int r = 0; r < 4; ++r) {
                            int grow = rowbase + p * 16 + quad * 4 + r;
                            if (grow < Mrows) {
                                int bb = (grow >= Lo) ? 1 : 0;
                                int t = grow - bb * Lo;
                                int ii = t + o, jj = t;
                                dots[(((size_t)bb * NHEAD + h) * SEQ + ii) * SEQ + jj] =
                                    0.14433756729740643f * dv[r];
                            }
                        }
                    }
                }
            }
            __syncthreads();
        }
    }
}

// ---------------- Kernel 4: fused causal softmax + attn@v -> inner (bf16) ----------
__global__ __launch_bounds__(256) void attn_kernel(const float* __restrict__ dots,
                                                   const float* __restrict__ v,
                                                   unsigned short* __restrict__ inner) {
    __shared__ float p_lds[8 * 200];
    const int i = blockIdx.x;
    const int b = blockIdx.y;
    const int tid = threadIdx.x;
    const int wave = tid >> 6, lane = tid & 63;
    const int n = i + 1;
#pragma unroll
    for (int hh = 0; hh < 2; ++hh) {
        int h = wave * 2 + hh;
        const float* drow = dots + (((size_t)b * NHEAD + h) * SEQ + i) * SEQ;
        float x0 = (lane < n) ? drow[lane] : -1e30f;
        float x1 = (lane + 64 < n) ? drow[lane + 64] : -1e30f;
        float x2 = (lane + 128 < n) ? drow[lane + 128] : -1e30f;
        float m = fmaxf(x0, fmaxf(x1, x2));
#pragma unroll
        for (int off = 32; off > 0; off >>= 1) m = fmaxf(m, __shfl_xor(m, off, 64));
        float e0 = __expf(x0 - m), e1 = __expf(x1 - m), e2 = __expf(x2 - m);
        float s = e0 + e1 + e2;
#pragma unroll
        for (int off = 32; off > 0; off >>= 1) s += __shfl_xor(s, off, 64);
        float rinv = 1.f / s;
        p_lds[h * 200 + lane] = e0 * rinv;
        p_lds[h * 200 + lane + 64] = e1 * rinv;
        p_lds[h * 200 + lane + 128] = e2 * rinv;
    }
    __syncthreads();
    const int e0 = tid;
    const int h0 = e0 / 48;
    const float* p0 = p_lds + h0 * 200;
    const int h1 = (tid < 128) ? (tid + 256) / 48 : 0;
    const float* p1 = p_lds + h1 * 200;
    const float* vb = v + (size_t)b * SEQ * DIMK;
    float a0 = 0.f, a1 = 0.f;
    const bool lo = (tid < 128);  // wave-uniform (waves 0,1)
#pragma unroll 4
    for (int j = 0; j < n; ++j) {
        a0 = fmaf(p0[j], vb[(size_t)j * DIMK + e0], a0);
        if (lo) a1 = fmaf(p1[j], vb[(size_t)j * DIMK + tid + 256], a1);
    }
    inner[((size_t)b * SEQ + i) * DIMK + e0] = f2bf(a0);
    if (lo) inner[((size_t)b * SEQ + i) * DIMK + tid + 256] = f2bf(a1);
}

// ---------------- Kernel 5: output projection + bias ----------
__global__ __launch_bounds__(256) void proj_kernel(const unsigned short* __restrict__ inner,
                                                   const float* __restrict__ wo,
                                                   const float* __restrict__ bo,
                                                   float* __restrict__ out) {
    __shared__ __align__(16) char lds_raw[6144];
    gemm384_48(inner, wo, out, bo, blockIdx.x * DHEAD, lds_raw);
}

extern "C" void kernel_launch(void* const* d_in, const int* in_sizes, int n_in,
                              void* d_out, int out_size, void* d_ws, size_t ws_size,
                              hipStream_t stream) {
    const float* x = (const float*)d_in[0];
    const float* gamma = (const float*)d_in[1];
    const float* beta = (const float*)d_in[2];
    const float* uq = (const float*)d_in[3];
    const float* uk = (const float*)d_in[4];
    const float* wv = (const float*)d_in[5];
    const float* wo = (const float*)d_in[6];
    const float* bo = (const float*)d_in[7];
    float* out = (float*)d_out;

    char* ws = (char*)d_ws;
    unsigned short* xn = (unsigned short*)ws;                       // 294912 B
    float* dots = (float*)(ws + 294912);                            // 2359296 B
    float* v = (float*)(ws + 294912 + 2359296);                     // 589824 B
    unsigned short* inner = (unsigned short*)(ws + 294912 + 2359296 + 589824);  // 294912 B

    ln_kernel<<<NB * SEQ, 64, 0, stream>>>(x, gamma, beta, xn);
    qk_dots_kernel<<<1536 + 8, 256, 0, stream>>>(xn, uq, uk, wv, dots, v);
    attn_kernel<<<dim3(SEQ, NB), 256, 0, stream>>>(dots, v, inner);
    proj_kernel<<<NHEAD, 256, 0, stream>>>(inner, wo, bo, out);
}

// Round 2
// 405.028 us; speedup vs baseline: 1.2565x; 1.2565x over previous
//
#include <hip/hip_runtime.h>

#define SEQ 192
#define DIMK 384
#define NHEAD 8
#define DHEAD 48
#define NB 2
#define SOFF (64 * 49)  // LDS floats per staged matrix slab

typedef __attribute__((ext_vector_type(8))) short short8;
typedef __attribute__((ext_vector_type(4))) float f32x4;
typedef __attribute__((ext_vector_type(4))) unsigned int u32x4;

__device__ __forceinline__ unsigned short f2bf(float f) {
    unsigned int u = __builtin_bit_cast(unsigned int, f);
    u += 0x7FFFu + ((u >> 16) & 1u);
    return (unsigned short)(u >> 16);
}
__device__ __forceinline__ unsigned pack2(float a, float b) {
    return (unsigned)f2bf(a) | ((unsigned)f2bf(b) << 16);
}

// ---------------- Kernel 1: LayerNorm -> bf16 xn ----------------
__global__ __launch_bounds__(64) void ln_kernel(const float* __restrict__ x,
                                                const float* __restrict__ gamma,
                                                const float* __restrict__ beta,
                                                unsigned short* __restrict__ xn) {
    int row = blockIdx.x;
    int l = threadIdx.x;
    const float* xr = x + (size_t)row * DIMK;
    float v[6];
    float s = 0.f, s2 = 0.f;
#pragma unroll
    for (int k = 0; k < 6; ++k) {
        v[k] = xr[l + 64 * k];
        s += v[k];
        s2 += v[k] * v[k];
    }
#pragma unroll
    for (int off = 32; off > 0; off >>= 1) {
        s += __shfl_xor(s, off, 64);
        s2 += __shfl_xor(s2, off, 64);
    }
    float mu = s * (1.f / 384.f);
    float var = s2 * (1.f / 384.f) - mu * mu;
    float inv = rsqrtf(var + 1e-5f);
#pragma unroll
    for (int k = 0; k < 6; ++k) {
        int c = l + 64 * k;
        float o = (v[k] - mu) * inv * gamma[c] + beta[c];
        xn[(size_t)row * DIMK + c] = f2bf(o);
    }
}

// ---------------- generic 192-row x 48-col GEMM tile (for v and out proj) ----
// A bf16 [384][384], W fp32 [384][384]; block=256 (4 waves), wave = 48 rows.
__device__ __forceinline__ void gemm192(const unsigned short* __restrict__ A,
                                        const float* __restrict__ W,
                                        const float* __restrict__ bias,
                                        float* __restrict__ outp,
                                        int rowg, int colg, float* lds_f, int tid) {
    const int wave = tid >> 6, lane = tid & 63, quad = lane >> 4, l15 = lane & 15;
    const int nbase = colg * 48;
    const float* gp[3];
    int la[3];
#pragma unroll
    for (int it = 0; it < 3; ++it) {
        int idx = tid + 256 * it;  // < 768
        int r = idx / 12, n0 = (idx % 12) * 4;
        gp[it] = W + (size_t)r * DIMK + nbase + n0;
        la[it] = r * 49 + n0;
    }
    const unsigned short* aptr[3];
#pragma unroll
    for (int p = 0; p < 3; ++p) {
        int row = rowg * 192 + wave * 48 + p * 16 + l15;
        aptr[p] = A + (size_t)row * DIMK + quad * 8;
    }
    f32x4 acc[3][3];
#pragma unroll
    for (int p = 0; p < 3; ++p)
#pragma unroll
        for (int nt = 0; nt < 3; ++nt) acc[p][nt] = f32x4{0.f, 0.f, 0.f, 0.f};
    f32x4 cur[3];
#pragma unroll
    for (int it = 0; it < 3; ++it) cur[it] = *(const f32x4*)gp[it];
    for (int c = 0; c < 6; ++c) {
#pragma unroll
        for (int it = 0; it < 3; ++it) {
            float* d = lds_f + la[it];
            d[0] = cur[it].x;
            d[1] = cur[it].y;
            d[2] = cur[it].z;
            d[3] = cur[it].w;
        }
        __syncthreads();
        if (c < 5) {
#pragma unroll
            for (int it = 0; it < 3; ++it)
                cur[it] = *(const f32x4*)(gp[it] + (size_t)(c + 1) * 64 * DIMK);
        }
        short8 afr[6];
#pragma unroll
        for (int p = 0; p < 3; ++p)
#pragma unroll
            for (int kk = 0; kk < 2; ++kk)
                afr[p * 2 + kk] =
                    __builtin_bit_cast(short8, *(const u32x4*)(aptr[p] + c * 64 + kk * 32));
#pragma unroll
        for (int kk = 0; kk < 2; ++kk) {
            short8 bfr[3];
#pragma unroll
            for (int nt = 0; nt < 3; ++nt) {
                const float* bsrc = lds_f + (kk * 32 + quad * 8) * 49 + nt * 16 + l15;
                u32x4 pk;
                pk.x = pack2(bsrc[0], bsrc[49]);
                pk.y = pack2(bsrc[98], bsrc[147]);
                pk.z = pack2(bsrc[196], bsrc[245]);
                pk.w = pack2(bsrc[294], bsrc[343]);
                bfr[nt] = __builtin_bit_cast(short8, pk);
            }
#pragma unroll
            for (int p = 0; p < 3; ++p)
#pragma unroll
                for (int nt = 0; nt < 3; ++nt)
                    acc[p][nt] = __builtin_amdgcn_mfma_f32_16x16x32_bf16(afr[p * 2 + kk], bfr[nt],
                                                                         acc[p][nt], 0, 0, 0);
        }
        __syncthreads();
    }
#pragma unroll
    for (int p = 0; p < 3; ++p)
#pragma unroll
        for (int nt = 0; nt < 3; ++nt) {
            int col = nbase + nt * 16 + l15;
            float badd = bias ? bias[col] : 0.f;
#pragma unroll
            for (int rr = 0; rr < 4; ++rr) {
                int row = rowg * 192 + wave * 48 + p * 16 + quad * 4 + rr;
                outp[(size_t)row * DIMK + col] = acc[p][nt][rr] + badd;
            }
        }
}

// ---------------- Kernel 2: per-(offset,head,pass) QK dots + folded v ----------
// bx < 2304: qk job. bx in [2304,2320): v projection job.
__global__ __launch_bounds__(256) void qk_kernel(const unsigned short* __restrict__ xn,
                                                 const float* __restrict__ uq,
                                                 const float* __restrict__ uk,
                                                 const float* __restrict__ wv,
                                                 float* __restrict__ dots,
                                                 float* __restrict__ vout) {
    __shared__ float lds_f[2 * SOFF];  // 25088 B
    const int bx = blockIdx.x;
    const int tid = threadIdx.x;
    if (bx >= 2304) {
        int id = bx - 2304;
        gemm192(xn, wv, nullptr, vout, id & 1, id >> 1, lds_f, tid);
        return;
    }
    const int wave = tid >> 6, lane = tid & 63, quad = lane >> 4, l15 = lane & 15;
    const int h = bx / 288;
    int rem = bx % 288;
    int o, pass;
    if (rem < 192) {
        o = rem >> 1;
        pass = rem & 1;
    } else {
        o = rem - 96;
        pass = 0;
    }
    const int Lo = SEQ - o, Mrows = 2 * Lo;
    const int side = wave >> 1, wrow = wave & 1;
    const int rowbase = pass * 192 + wrow * 96;
    const bool active = rowbase < Mrows;
    const float* Wq = uq + (size_t)(191 - o) * (DIMK * DIMK);
    const float* Wk = uk + (size_t)o * (DIMK * DIMK);
    const int hbase = h * DHEAD;

    // staging decode: 1536 float4 per chunk (2 matrices x 64 k x 12 segs)
    const float* gp[6];
    int la[6];
#pragma unroll
    for (int it = 0; it < 6; ++it) {
        int idx = tid + 256 * it;
        int m = idx / 768, r2 = idx % 768;
        int r = r2 / 12, n0 = (r2 % 12) * 4;
        gp[it] = (m ? Wk : Wq) + (size_t)r * DIMK + hbase + n0;
        la[it] = (m * 64 + r) * 49 + n0;
    }
    // A-fragment row pointers (hoisted; row map independent of k-chunk)
    const unsigned short* aptr[6];
#pragma unroll
    for (int p = 0; p < 6; ++p) {
        int r = rowbase + p * 16 + l15;
        int bb = (r >= Lo) ? 1 : 0;
        int t = r - bb * Lo;
        int g = bb * SEQ + t + (side == 0 ? o : 0);
        if (r >= Mrows) g = 0;
        aptr[p] = xn + (size_t)g * DIMK + quad * 8;
    }

    f32x4 acc[6][3];
#pragma unroll
    for (int p = 0; p < 6; ++p)
#pragma unroll
        for (int nt = 0; nt < 3; ++nt) acc[p][nt] = f32x4{0.f, 0.f, 0.f, 0.f};

    f32x4 cur[6];
#pragma unroll
    for (int it = 0; it < 6; ++it) cur[it] = *(const f32x4*)gp[it];

    for (int c = 0; c < 6; ++c) {
#pragma unroll
        for (int it = 0; it < 6; ++it) {
            float* d = lds_f + la[it];
            d[0] = cur[it].x;
            d[1] = cur[it].y;
            d[2] = cur[it].z;
            d[3] = cur[it].w;
        }
        __syncthreads();
        // prefetch next chunk (in flight across the whole MFMA phase)
        if (c < 5) {
#pragma unroll
            for (int it = 0; it < 6; ++it)
                cur[it] = *(const f32x4*)(gp[it] + (size_t)(c + 1) * 64 * DIMK);
        }
        if (active) {
            short8 afr[12];
#pragma unroll
            for (int p = 0; p < 6; ++p)
#pragma unroll
                for (int kk = 0; kk < 2; ++kk)
                    afr[p * 2 + kk] =
                        __builtin_bit_cast(short8, *(const u32x4*)(aptr[p] + c * 64 + kk * 32));
#pragma unroll
            for (int kk = 0; kk < 2; ++kk) {
                short8 bfr[3];
#pragma unroll
                for (int nt = 0; nt < 3; ++nt) {
                    const float* bsrc =
                        lds_f + side * SOFF + (kk * 32 + quad * 8) * 49 + nt * 16 + l15;
                    u32x4 pk;
                    pk.x = pack2(bsrc[0], bsrc[49]);
                    pk.y = pack2(bsrc[98], bsrc[147]);
                    pk.z = pack2(bsrc[196], bsrc[245]);
                    pk.w = pack2(bsrc[294], bsrc[343]);
                    bfr[nt] = __builtin_bit_cast(short8, pk);
                }
#pragma unroll
                for (int p = 0; p < 6; ++p)
#pragma unroll
                    for (int nt = 0; nt < 3; ++nt)
                        acc[p][nt] = __builtin_amdgcn_mfma_f32_16x16x32_bf16(
                            afr[p * 2 + kk], bfr[nt], acc[p][nt], 0, 0, 0);
            }
        }
        __syncthreads();
    }

    // ---- epilogue: pair Q (waves 0,1) with K (waves 2,3) via LDS ----
    float* epi = lds_f;
#pragma unroll
    for (int ph = 0; ph < 2; ++ph) {
        if (side == 1 && wrow == ph && active) {
#pragma unroll
            for (int p = 0; p < 6; ++p)
#pragma unroll
                for (int nt = 0; nt < 3; ++nt)
#pragma unroll
                    for (int r = 0; r < 4; ++r)
                        epi[((p * 3 + nt) * 4 + r) * 64 + lane] = acc[p][nt][r];
        }
        __syncthreads();
        if (side == 0 && wrow == ph && active) {
#pragma unroll
            for (int p = 0; p < 6; ++p) {
                float d0 = 0.f, d1 = 0.f, d2 = 0.f, d3 = 0.f;
#pragma unroll
                for (int nt = 0; nt < 3; ++nt) {
                    d0 += acc[p][nt][0] * epi[((p * 3 + nt) * 4 + 0) * 64 + lane];
                    d1 += acc[p][nt][1] * epi[((p * 3 + nt) * 4 + 1) * 64 + lane];
                    d2 += acc[p][nt][2] * epi[((p * 3 + nt) * 4 + 2) * 64 + lane];
                    d3 += acc[p][nt][3] * epi[((p * 3 + nt) * 4 + 3) * 64 + lane];
                }
#pragma unroll
                for (int mm = 1; mm <= 8; mm <<= 1) {
                    d0 += __shfl_xor(d0, mm, 64);
                    d1 += __shfl_xor(d1, mm, 64);
                    d2 += __shfl_xor(d2, mm, 64);
                    d3 += __shfl_xor(d3, mm, 64);
                }
                if (l15 == 0) {
                    float dv[4] = {d0, d1, d2, d3};
#pragma unroll
                    for (int r = 0; r < 4; ++r) {
                        int grow = rowbase + p * 16 + quad * 4 + r;
                        if (grow < Mrows) {
                            int bb = (grow >= Lo) ? 1 : 0;
                            int t = grow - bb * Lo;
                            int ii = t + o, jj = t;
                            dots[(((size_t)bb * NHEAD + h) * SEQ + ii) * SEQ + jj] =
                                0.14433756729740643f * dv[r];
                        }
                    }
                }
            }
        }
        __syncthreads();
    }
}

// ---------------- Kernel 3: fused causal softmax + attn@v -> inner (bf16) ----------
__global__ __launch_bounds__(256) void attn_kernel(const float* __restrict__ dots,
                                                   const float* __restrict__ v,
                                                   unsigned short* __restrict__ inner) {
    __shared__ float p_lds[8 * 200];
    const int i = blockIdx.x;
    const int b = blockIdx.y;
    const int tid = threadIdx.x;
    const int wave = tid >> 6, lane = tid & 63;
    const int n = i + 1;
#pragma unroll
    for (int hh = 0; hh < 2; ++hh) {
        int h = wave * 2 + hh;
        const float* drow = dots + (((size_t)b * NHEAD + h) * SEQ + i) * SEQ;
        float x0 = (lane < n) ? drow[lane] : -1e30f;
        float x1 = (lane + 64 < n) ? drow[lane + 64] : -1e30f;
        float x2 = (lane + 128 < n) ? drow[lane + 128] : -1e30f;
        float m = fmaxf(x0, fmaxf(x1, x2));
#pragma unroll
        for (int off = 32; off > 0; off >>= 1) m = fmaxf(m, __shfl_xor(m, off, 64));
        float e0 = __expf(x0 - m), e1 = __expf(x1 - m), e2 = __expf(x2 - m);
        float s = e0 + e1 + e2;
#pragma unroll
        for (int off = 32; off > 0; off >>= 1) s += __shfl_xor(s, off, 64);
        float rinv = 1.f / s;
        p_lds[h * 200 + lane] = e0 * rinv;
        p_lds[h * 200 + lane + 64] = e1 * rinv;
        p_lds[h * 200 + lane + 128] = e2 * rinv;
    }
    __syncthreads();
    const int e0 = tid;
    const int h0 = e0 / 48;
    const float* p0 = p_lds + h0 * 200;
    const int h1 = (tid < 128) ? (tid + 256) / 48 : 0;
    const float* p1 = p_lds + h1 * 200;
    const float* vb = v + (size_t)b * SEQ * DIMK;
    float a0 = 0.f, a1 = 0.f;
    const bool lo = (tid < 128);  // wave-uniform (waves 0,1)
#pragma unroll 4
    for (int j = 0; j < n; ++j) {
        a0 = fmaf(p0[j], vb[(size_t)j * DIMK + e0], a0);
        if (lo) a1 = fmaf(p1[j], vb[(size_t)j * DIMK + tid + 256], a1);
    }
    inner[((size_t)b * SEQ + i) * DIMK + e0] = f2bf(a0);
    if (lo) inner[((size_t)b * SEQ + i) * DIMK + tid + 256] = f2bf(a1);
}

// ---------------- Kernel 4: output projection + bias ----------
__global__ __launch_bounds__(256) void proj_kernel(const unsigned short* __restrict__ inner,
                                                   const float* __restrict__ wo,
                                                   const float* __restrict__ bo,
                                                   float* __restrict__ out) {
    __shared__ float lds_f[SOFF];
    int id = blockIdx.x;  // 16 blocks: (colg, rowg)
    gemm192(inner, wo, bo, out, id & 1, id >> 1, lds_f, threadIdx.x);
}

extern "C" void kernel_launch(void* const* d_in, const int* in_sizes, int n_in,
                              void* d_out, int out_size, void* d_ws, size_t ws_size,
                              hipStream_t stream) {
    const float* x = (const float*)d_in[0];
    const float* gamma = (const float*)d_in[1];
    const float* beta = (const float*)d_in[2];
    const float* uq = (const float*)d_in[3];
    const float* uk = (const float*)d_in[4];
    const float* wv = (const float*)d_in[5];
    const float* wo = (const float*)d_in[6];
    const float* bo = (const float*)d_in[7];
    float* out = (float*)d_out;

    char* ws = (char*)d_ws;
    unsigned short* xn = (unsigned short*)ws;                                   // 294912 B
    float* dots = (float*)(ws + 294912);                                        // 2359296 B
    float* v = (float*)(ws + 294912 + 2359296);                                 // 589824 B
    unsigned short* inner = (unsigned short*)(ws + 294912 + 2359296 + 589824);  // 294912 B

    ln_kernel<<<NB * SEQ, 64, 0, stream>>>(x, gamma, beta, xn);
    qk_kernel<<<2320, 256, 0, stream>>>(xn, uq, uk, wv, dots, v);
    attn_kernel<<<dim3(SEQ, NB), 256, 0, stream>>>(dots, v, inner);
    proj_kernel<<<16, 256, 0, stream>>>(inner, wo, bo, out);
}

// Round 4
// 383.687 us; speedup vs baseline: 1.3264x; 1.0556x over previous
//
#include <hip/hip_runtime.h>

#define SEQ 192
#define DIMK 384
#define NHEAD 8
#define DHEAD 48
#define NB 2
#define SOFF (64 * 49)  // LDS floats per staged slab in gemm192 (padded path)

typedef __attribute__((ext_vector_type(8))) short short8;
typedef __attribute__((ext_vector_type(4))) float f32x4;
typedef __attribute__((ext_vector_type(4))) unsigned int u32x4;

__device__ __forceinline__ unsigned short f2bf(float f) {
    unsigned int u = __builtin_bit_cast(unsigned int, f);
    u += 0x7FFFu + ((u >> 16) & 1u);
    return (unsigned short)(u >> 16);
}
__device__ __forceinline__ unsigned pack2(float a, float b) {
    return (unsigned)f2bf(a) | ((unsigned)f2bf(b) << 16);
}
// async global->LDS DMA, 16B per lane; LDS dst = wave-uniform base + lane*16
__device__ __forceinline__ void dma16(const float* g, void* l) {
    __builtin_amdgcn_global_load_lds((const __attribute__((address_space(1))) void*)g,
                                     (__attribute__((address_space(3))) void*)l, 16, 0, 0);
}

// ---------------- Kernel 1: LayerNorm -> bf16 xn ----------------
__global__ __launch_bounds__(64) void ln_kernel(const float* __restrict__ x,
                                                const float* __restrict__ gamma,
                                                const float* __restrict__ beta,
                                                unsigned short* __restrict__ xn) {
    int row = blockIdx.x;
    int l = threadIdx.x;
    const float* xr = x + (size_t)row * DIMK;
    float v[6];
    float s = 0.f, s2 = 0.f;
#pragma unroll
    for (int k = 0; k < 6; ++k) {
        v[k] = xr[l + 64 * k];
        s += v[k];
        s2 += v[k] * v[k];
    }
#pragma unroll
    for (int off = 32; off > 0; off >>= 1) {
        s += __shfl_xor(s, off, 64);
        s2 += __shfl_xor(s2, off, 64);
    }
    float mu = s * (1.f / 384.f);
    float var = s2 * (1.f / 384.f) - mu * mu;
    float inv = rsqrtf(var + 1e-5f);
#pragma unroll
    for (int k = 0; k < 6; ++k) {
        int c = l + 64 * k;
        float o = (v[k] - mu) * inv * gamma[c] + beta[c];
        xn[(size_t)row * DIMK + c] = f2bf(o);
    }
}

// ---------------- generic 192-row x 48-col GEMM tile (for v and out proj) ----
__device__ __forceinline__ void gemm192(const unsigned short* __restrict__ A,
                                        const float* __restrict__ W,
                                        const float* __restrict__ bias,
                                        float* __restrict__ outp,
                                        int rowg, int colg, float* lds_f, int tid) {
    const int wave = tid >> 6, lane = tid & 63, quad = lane >> 4, l15 = lane & 15;
    const int nbase = colg * 48;
    const float* gp[3];
    int la[3];
#pragma unroll
    for (int it = 0; it < 3; ++it) {
        int idx = tid + 256 * it;  // < 768
        int r = idx / 12, n0 = (idx % 12) * 4;
        gp[it] = W + (size_t)r * DIMK + nbase + n0;
        la[it] = r * 49 + n0;
    }
    const unsigned short* aptr[3];
#pragma unroll
    for (int p = 0; p < 3; ++p) {
        int row = rowg * 192 + wave * 48 + p * 16 + l15;
        aptr[p] = A + (size_t)row * DIMK + quad * 8;
    }
    f32x4 acc[3][3];
#pragma unroll
    for (int p = 0; p < 3; ++p)
#pragma unroll
        for (int nt = 0; nt < 3; ++nt) acc[p][nt] = f32x4{0.f, 0.f, 0.f, 0.f};
    f32x4 cur[3];
#pragma unroll
    for (int it = 0; it < 3; ++it) cur[it] = *(const f32x4*)gp[it];
    for (int c = 0; c < 6; ++c) {
#pragma unroll
        for (int it = 0; it < 3; ++it) {
            float* d = lds_f + la[it];
            d[0] = cur[it].x;
            d[1] = cur[it].y;
            d[2] = cur[it].z;
            d[3] = cur[it].w;
        }
        __syncthreads();
        if (c < 5) {
#pragma unroll
            for (int it = 0; it < 3; ++it)
                cur[it] = *(const f32x4*)(gp[it] + (size_t)(c + 1) * 64 * DIMK);
        }
        short8 afr[6];
#pragma unroll
        for (int p = 0; p < 3; ++p)
#pragma unroll
            for (int kk = 0; kk < 2; ++kk)
                afr[p * 2 + kk] =
                    __builtin_bit_cast(short8, *(const u32x4*)(aptr[p] + c * 64 + kk * 32));
#pragma unroll
        for (int kk = 0; kk < 2; ++kk) {
            short8 bfr[3];
#pragma unroll
            for (int nt = 0; nt < 3; ++nt) {
                const float* bsrc = lds_f + (kk * 32 + quad * 8) * 49 + nt * 16 + l15;
                u32x4 pk;
                pk.x = pack2(bsrc[0], bsrc[49]);
                pk.y = pack2(bsrc[98], bsrc[147]);
                pk.z = pack2(bsrc[196], bsrc[245]);
                pk.w = pack2(bsrc[294], bsrc[343]);
                bfr[nt] = __builtin_bit_cast(short8, pk);
            }
#pragma unroll
            for (int p = 0; p < 3; ++p)
#pragma unroll
                for (int nt = 0; nt < 3; ++nt)
                    acc[p][nt] = __builtin_amdgcn_mfma_f32_16x16x32_bf16(afr[p * 2 + kk], bfr[nt],
                                                                         acc[p][nt], 0, 0, 0);
        }
        __syncthreads();
    }
#pragma unroll
    for (int p = 0; p < 3; ++p)
#pragma unroll
        for (int nt = 0; nt < 3; ++nt) {
            int col = nbase + nt * 16 + l15;
            float badd = bias ? bias[col] : 0.f;
#pragma unroll
            for (int rr = 0; rr < 4; ++rr) {
                int row = rowg * 192 + wave * 48 + p * 16 + quad * 4 + rr;
                outp[(size_t)row * DIMK + col] = acc[p][nt][rr] + badd;
            }
        }
}

// ---------------- Kernel 2: per-(offset,head,pass) QK dots + folded v ----------
// bx < 2304: qk job (bx = h*288 + rem). bx in [2304,2320): v projection job.
// Staging: global_load_lds width16, double-buffered LDS [2][2][64][48] fp32.
__global__ __launch_bounds__(256, 3) void qk_kernel(const unsigned short* __restrict__ xn,
                                                    const float* __restrict__ uq,
                                                    const float* __restrict__ uk,
                                                    const float* __restrict__ wv,
                                                    float* __restrict__ dots,
                                                    float* __restrict__ vout) {
    __shared__ __align__(16) float lds_f[2 * 6144];  // 49152 B: two 24.6 KB chunk buffers
    const int bx = blockIdx.x;
    const int tid = threadIdx.x;
    if (bx >= 2304) {
        int id = bx - 2304;
        gemm192(xn, wv, nullptr, vout, id & 1, id >> 1, lds_f, tid);
        return;
    }
    const int wave = tid >> 6, lane = tid & 63, quad = lane >> 4, l15 = lane & 15;
    const int h = bx / 288;
    int rem = bx % 288;
    int o, pass;
    if (rem < 192) {
        o = rem >> 1;
        pass = rem & 1;
    } else {
        o = rem - 96;
        pass = 0;
    }
    const int Lo = SEQ - o, Mrows = 2 * Lo;
    const int side = wave >> 1, wrow = wave & 1;
    const int rowbase = pass * 192 + wrow * 96;
    const bool active = rowbase < Mrows;
    const float* Wq = uq + (size_t)(191 - o) * (DIMK * DIMK);
    const float* Wk = uk + (size_t)o * (DIMK * DIMK);
    const int hbase = h * DHEAD;

    // ---- DMA plan: 24 instructions/chunk, 6 per wave. unit u = t*64+lane ----
    // u -> (m = u/768, r = (u%768)/12, n4 = (u%768)%12); LDS byte = buf + u*16.
    const float* gsrc[6];
    unsigned ldsb[6];
#pragma unroll
    for (int i = 0; i < 6; ++i) {
        int t = wave * 6 + i;
        int u = t * 64 + lane;
        int m = (u >= 768) ? 1 : 0;
        int q = u - m * 768;
        int r = q / 12, n4 = q % 12;
        gsrc[i] = (m ? Wk : Wq) + (size_t)r * DIMK + hbase + n4 * 4;
        ldsb[i] = (unsigned)t * 1024u;
    }
    // A-fragment row pointers (row map independent of k-chunk)
    const unsigned short* aptr[6];
#pragma unroll
    for (int p = 0; p < 6; ++p) {
        int r = rowbase + p * 16 + l15;
        int bb = (r >= Lo) ? 1 : 0;
        int t = r - bb * Lo;
        int g = bb * SEQ + t + (side == 0 ? o : 0);
        if (r >= Mrows) g = 0;
        aptr[p] = xn + (size_t)g * DIMK + quad * 8;
    }

    f32x4 acc[6][3];
#pragma unroll
    for (int p = 0; p < 6; ++p)
#pragma unroll
        for (int nt = 0; nt < 3; ++nt) acc[p][nt] = f32x4{0.f, 0.f, 0.f, 0.f};

    // prologue: DMA chunk 0 into buffer 0
#pragma unroll
    for (int i = 0; i < 6; ++i) dma16(gsrc[i], (char*)lds_f + ldsb[i]);

    for (int c = 0; c < 6; ++c) {
        __syncthreads();  // drains DMA for buf[c&1]; fences prior reads of buf[(c+1)&1]
        if (c < 5) {
            unsigned nb = ((unsigned)(c + 1) & 1u) * 24576u;
#pragma unroll
            for (int i = 0; i < 6; ++i)
                dma16(gsrc[i] + (size_t)(c + 1) * 24576, (char*)lds_f + nb + ldsb[i]);
        }
        if (active) {
            const float* buf = lds_f + (c & 1) * 6144 + side * 3072;
            short8 afr[12];
#pragma unroll
            for (int p = 0; p < 6; ++p)
#pragma unroll
                for (int kk = 0; kk < 2; ++kk)
                    afr[p * 2 + kk] =
                        __builtin_bit_cast(short8, *(const u32x4*)(aptr[p] + c * 64 + kk * 32));
#pragma unroll
            for (int kk = 0; kk < 2; ++kk) {
                short8 bfr[3];
#pragma unroll
                for (int nt = 0; nt < 3; ++nt) {
                    const float* bsrc = buf + (kk * 32 + quad * 8) * 48 + nt * 16 + l15;
                    u32x4 pk;
                    pk.x = pack2(bsrc[0], bsrc[48]);
                    pk.y = pack2(bsrc[96], bsrc[144]);
                    pk.z = pack2(bsrc[192], bsrc[240]);
                    pk.w = pack2(bsrc[288], bsrc[336]);
                    bfr[nt] = __builtin_bit_cast(short8, pk);
                }
#pragma unroll
                for (int p = 0; p < 6; ++p)
#pragma unroll
                    for (int nt = 0; nt < 3; ++nt)
                        acc[p][nt] = __builtin_amdgcn_mfma_f32_16x16x32_bf16(
                            afr[p * 2 + kk], bfr[nt], acc[p][nt], 0, 0, 0);
            }
        }
    }
    __syncthreads();

    // ---- epilogue: pair Q (waves 0,1) with K (waves 2,3) via LDS ----
    float* epi = lds_f;
#pragma unroll
    for (int ph = 0; ph < 2; ++ph) {
        if (side == 1 && wrow == ph && active) {
#pragma unroll
            for (int p = 0; p < 6; ++p)
#pragma unroll
                for (int nt = 0; nt < 3; ++nt)
#pragma unroll
                    for (int r = 0; r < 4; ++r)
                        epi[((p * 3 + nt) * 4 + r) * 64 + lane] = acc[p][nt][r];
        }
        __syncthreads();
        if (side == 0 && wrow == ph && active) {
#pragma unroll
            for (int p = 0; p < 6; ++p) {
                float d0 = 0.f, d1 = 0.f, d2 = 0.f, d3 = 0.f;
#pragma unroll
                for (int nt = 0; nt < 3; ++nt) {
                    d0 += acc[p][nt][0] * epi[((p * 3 + nt) * 4 + 0) * 64 + lane];
                    d1 += acc[p][nt][1] * epi[((p * 3 + nt) * 4 + 1) * 64 + lane];
                    d2 += acc[p][nt][2] * epi[((p * 3 + nt) * 4 + 2) * 64 + lane];
                    d3 += acc[p][nt][3] * epi[((p * 3 + nt) * 4 + 3) * 64 + lane];
                }
#pragma unroll
                for (int mm = 1; mm <= 8; mm <<= 1) {
                    d0 += __shfl_xor(d0, mm, 64);
                    d1 += __shfl_xor(d1, mm, 64);
                    d2 += __shfl_xor(d2, mm, 64);
                    d3 += __shfl_xor(d3, mm, 64);
                }
                if (l15 == 0) {
                    float dv[4] = {d0, d1, d2, d3};
#pragma unroll
                    for (int r = 0; r < 4; ++r) {
                        int grow = rowbase + p * 16 + quad * 4 + r;
                        if (grow < Mrows) {
                            int bb = (grow >= Lo) ? 1 : 0;
                            int t = grow - bb * Lo;
                            int ii = t + o, jj = t;
                            dots[(((size_t)bb * NHEAD + h) * SEQ + ii) * SEQ + jj] =
                                0.14433756729740643f * dv[r];
                        }
                    }
                }
            }
        }
        __syncthreads();
    }
}

// ---------------- Kernel 3: fused causal softmax + attn@v -> inner (bf16) ----------
__global__ __launch_bounds__(256) void attn_kernel(const float* __restrict__ dots,
                                                   const float* __restrict__ v,
                                                   unsigned short* __restrict__ inner) {
    __shared__ float p_lds[8 * 200];
    const int i = blockIdx.x;
    const int b = blockIdx.y;
    const int tid = threadIdx.x;
    const int wave = tid >> 6, lane = tid & 63;
    const int n = i + 1;
#pragma unroll
    for (int hh = 0; hh < 2; ++hh) {
        int h = wave * 2 + hh;
        const float* drow = dots + (((size_t)b * NHEAD + h) * SEQ + i) * SEQ;
        float x0 = (lane < n) ? drow[lane] : -1e30f;
        float x1 = (lane + 64 < n) ? drow[lane + 64] : -1e30f;
        float x2 = (lane + 128 < n) ? drow[lane + 128] : -1e30f;
        float m = fmaxf(x0, fmaxf(x1, x2));
#pragma unroll
        for (int off = 32; off > 0; off >>= 1) m = fmaxf(m, __shfl_xor(m, off, 64));
        float e0 = __expf(x0 - m), e1 = __expf(x1 - m), e2 = __expf(x2 - m);
        float s = e0 + e1 + e2;
#pragma unroll
        for (int off = 32; off > 0; off >>= 1) s += __shfl_xor(s, off, 64);
        float rinv = 1.f / s;
        p_lds[h * 200 + lane] = e0 * rinv;
        p_lds[h * 200 + lane + 64] = e1 * rinv;
        p_lds[h * 200 + lane + 128] = e2 * rinv;
    }
    __syncthreads();
    const int e0 = tid;
    const int h0 = e0 / 48;
    const float* p0 = p_lds + h0 * 200;
    const int h1 = (tid < 128) ? (tid + 256) / 48 : 0;
    const float* p1 = p_lds + h1 * 200;
    const float* vb = v + (size_t)b * SEQ * DIMK;
    float a0 = 0.f, a1 = 0.f;
    const bool lo = (tid < 128);  // wave-uniform (waves 0,1)
#pragma unroll 4
    for (int j = 0; j < n; ++j) {
        a0 = fmaf(p0[j], vb[(size_t)j * DIMK + e0], a0);
        if (lo) a1 = fmaf(p1[j], vb[(size_t)j * DIMK + tid + 256], a1);
    }
    inner[((size_t)b * SEQ + i) * DIMK + e0] = f2bf(a0);
    if (lo) inner[((size_t)b * SEQ + i) * DIMK + tid + 256] = f2bf(a1);
}

// ---------------- Kernel 4: output projection + bias ----------
__global__ __launch_bounds__(256) void proj_kernel(const unsigned short* __restrict__ inner,
                                                   const float* __restrict__ wo,
                                                   const float* __restrict__ bo,
                                                   float* __restrict__ out) {
    __shared__ float lds_f[SOFF];
    int id = blockIdx.x;  // 16 blocks: (colg, rowg)
    gemm192(inner, wo, bo, out, id & 1, id >> 1, lds_f, threadIdx.x);
}

extern "C" void kernel_launch(void* const* d_in, const int* in_sizes, int n_in,
                              void* d_out, int out_size, void* d_ws, size_t ws_size,
                              hipStream_t stream) {
    const float* x = (const float*)d_in[0];
    const float* gamma = (const float*)d_in[1];
    const float* beta = (const float*)d_in[2];
    const float* uq = (const float*)d_in[3];
    const float* uk = (const float*)d_in[4];
    const float* wv = (const float*)d_in[5];
    const float* wo = (const float*)d_in[6];
    const float* bo = (const float*)d_in[7];
    float* out = (float*)d_out;

    char* ws = (char*)d_ws;
    unsigned short* xn = (unsigned short*)ws;                                   // 294912 B
    float* dots = (float*)(ws + 294912);                                        // 2359296 B
    float* v = (float*)(ws + 294912 + 2359296);                                 // 589824 B
    unsigned short* inner = (unsigned short*)(ws + 294912 + 2359296 + 589824);  // 294912 B

    ln_kernel<<<NB * SEQ, 64, 0, stream>>>(x, gamma, beta, xn);
    qk_kernel<<<2320, 256, 0, stream>>>(xn, uq, uk, wv, dots, v);
    attn_kernel<<<dim3(SEQ, NB), 256, 0, stream>>>(dots, v, inner);
    proj_kernel<<<16, 256, 0, stream>>>(inner, wo, bo, out);
}